// Round 8
// baseline (815.219 us; speedup 1.0000x reference)
//
#include <hip/hip_runtime.h>

#define NG 500
#define NPG 100
#define EPG 800
#define INDIM 64
#define HID 128
#define ETOT (NG*EPG)
#define NTOT (NG*NPG)
#define KKEEP 640
#define KDROP 160
#define MAXDEG 64

// output section offsets (in floats)
#define OFF_CX    0u
#define OFF_CEI   6400000u
#define OFF_CATTR 7040000u
#define OFF_CW    7360000u
#define OFF_CB    7680000u
#define OFF_FX    7730000u
#define OFF_FEI   14130000u
#define OFF_FATTR 14290000u
#define OFF_FW    14370000u
#define OFF_FB    14450000u
#define OFF_ES    14500000u

// ---------------------------------------------------------------------------
// prep: per-dst incoming edge lists as (ew, src) pairs + weighted degree.
// ---------------------------------------------------------------------------
__global__ __launch_bounds__(128) void prep_kernel(
    const int* __restrict__ ei, const float* __restrict__ ea,
    float2* __restrict__ elist2, int* __restrict__ ecnt, float* __restrict__ sdeg)
{
  __shared__ unsigned char esrcL[EPG];
  __shared__ unsigned char edstL[EPG];
  __shared__ float ewvL[EPG];
  const int g = blockIdx.x, t = threadIdx.x;
  const int nb = g * NPG;
  for (int e = t; e < EPG; e += 128) {
    int ge = g * EPG + e;
    esrcL[e] = (unsigned char)(ei[ge] - nb);
    edstL[e] = (unsigned char)(ei[ETOT + ge] - nb);
    ewvL[e] = ea[ge];
  }
  __syncthreads();
  if (t < NPG) {
    int cnt = 0; float s = 0.f;
    float2* lp = elist2 + (size_t)(nb + t) * MAXDEG;
    for (int e = 0; e < EPG; e++) {
      if ((int)edstL[e] == t) {
        if (cnt < MAXDEG) lp[cnt] = make_float2(ewvL[e], __int_as_float((int)esrcL[e]));
        cnt++; s += ewvL[e];
      }
    }
    ecnt[nb + t] = cnt < MAXDEG ? cnt : MAXDEG;
    sdeg[nb + t] = s;
  }
}

// ---------------------------------------------------------------------------
// preagg: y[d] = sum_e ew * x[src_e]
// ---------------------------------------------------------------------------
template<int K>
__global__ __launch_bounds__(512) void preagg_kernel(
    const float* __restrict__ xin, const float2* __restrict__ elist2,
    const int* __restrict__ ecnt, float* __restrict__ y)
{
  __shared__ float xt[NPG][K];
  const int g = blockIdx.x, t = threadIdx.x;
  const int nb = g * NPG;
  for (int i = t; i < NPG * K / 4; i += 512)
    ((float4*)xt)[i] = ((const float4*)(xin + (size_t)nb * K))[i];
  __syncthreads();
  const int c = t % K, grp = t / K;
  const int NGRP = 512 / K;
  for (int d = grp; d < NPG; d += NGRP) {
    const int cn = ecnt[nb + d];
    const float2* lp = elist2 + (size_t)(nb + d) * MAXDEG;
    float acc = 0.f;
    for (int j = 0; j < cn; j++) {
      float2 p = lp[j];
      acc += p.x * xt[__float_as_int(p.y)][c];
    }
    y[(size_t)(nb + d) * K + c] = acc;
  }
}

// ---------------------------------------------------------------------------
// conv GEMM: h = [y | x | sd*x] @ [w1; w3; -w2] + sd*b1 + b3  (opt relu)
// A-chunk staged in padded LDS.
// ---------------------------------------------------------------------------
template<int K, bool RELU>
__global__ __launch_bounds__(256) void conv_gemm_kernel(
    const float* __restrict__ y, const float* __restrict__ xin, const float* __restrict__ sdeg,
    const float* __restrict__ w1, const float* __restrict__ w2, const float* __restrict__ w3,
    const float* __restrict__ b1, const float* __restrict__ b3,
    float* __restrict__ hout)
{
  __shared__ float wl[64][HID];   // 32KB B' chunk
  __shared__ float al[128][68];   // 34.8KB A chunk
  const int t = threadIdx.x;
  const int m0 = blockIdx.x * 128;
  const int tc = t % 16;
  const int tr = t / 16;
  float acc[8][8];
#pragma unroll
  for (int i = 0; i < 8; i++)
#pragma unroll
    for (int j = 0; j < 8; j++) acc[i][j] = 0.f;

  int rowc[8]; float sdv[8];
#pragma unroll
  for (int i = 0; i < 8; i++) {
    int r = m0 + tr * 8 + i;
    rowc[i] = r < NTOT ? r : NTOT - 1;
    sdv[i] = sdeg[rowc[i]];
  }
  const int NCH = (3 * K) / 64;
  for (int ch = 0; ch < NCH; ++ch) {
    __syncthreads();
    const int seg = (ch * 64) / K;
    const int kb = (ch * 64) % K;
    for (int i = t; i < 64 * HID / 4; i += 256) {
      int kk = i / 32, q = i % 32;
      int kr = ch * 64 + kk;
      int sr = kr % K;
      const float* wp = seg == 0 ? w1 : (seg == 1 ? w3 : w2);
      float4 v = *(const float4*)(wp + (size_t)sr * HID + q * 4);
      if (seg == 2) { v.x = -v.x; v.y = -v.y; v.z = -v.z; v.w = -v.w; }
      *(float4*)&wl[kk][q * 4] = v;
    }
    {
      const float* abase = (seg == 0 ? y : xin);
      for (int i = t; i < 128 * 16; i += 256) {
        int r = i / 16, q = i % 16;
        int gr = m0 + r; if (gr >= NTOT) gr = NTOT - 1;
        float4 v = *(const float4*)(abase + (size_t)gr * K + kb + q * 4);
        if (seg == 2) { float s = sdeg[gr]; v.x *= s; v.y *= s; v.z *= s; v.w *= s; }
        *(float4*)&al[r][q * 4] = v;
      }
    }
    __syncthreads();
    for (int k4 = 0; k4 < 16; ++k4) {
      float4 a4[8];
#pragma unroll
      for (int i = 0; i < 8; i++)
        a4[i] = *(const float4*)&al[tr * 8 + i][k4 * 4];
#pragma unroll
      for (int kk = 0; kk < 4; kk++) {
        float wv0[4], wv1[4];
        *(float4*)wv0 = *(const float4*)&wl[k4 * 4 + kk][tc * 4];
        *(float4*)wv1 = *(const float4*)&wl[k4 * 4 + kk][64 + tc * 4];
#pragma unroll
        for (int i = 0; i < 8; i++) {
          const float av = (&a4[i].x)[kk];
#pragma unroll
          for (int j = 0; j < 4; j++) {
            acc[i][j]     += av * wv0[j];
            acc[i][4 + j] += av * wv1[j];
          }
        }
      }
    }
  }
#pragma unroll
  for (int i = 0; i < 8; i++) {
    const int r = m0 + tr * 8 + i;
    if (r < NTOT) {
      float4 o0, o1;
#pragma unroll
      for (int j = 0; j < 4; j++) {
        float c0 = acc[i][j]     + sdv[i] * b1[tc * 4 + j]      + b3[tc * 4 + j];
        float c1 = acc[i][4 + j] + sdv[i] * b1[64 + tc * 4 + j] + b3[64 + tc * 4 + j];
        if (RELU) { c0 = fmaxf(c0, 0.f); c1 = fmaxf(c1, 0.f); }
        (&o0.x)[j] = c0; (&o1.x)[j] = c1;
      }
      float* op = hout + (size_t)r * HID;
      *(float4*)(op + tc * 4) = o0;
      *(float4*)(op + 64 + tc * 4) = o1;
    }
  }
}

// ---------------------------------------------------------------------------
// pq_gemm v2: PQ[n][0:512] = h2@W1a (+b1), PQ[n][512:1024] = h2@W1b.
// 128x128 tiles, 8x8 register tiles, BOTH operands LDS-staged.
// ---------------------------------------------------------------------------
__global__ __launch_bounds__(256) void pq_gemm_kernel(
    const float* __restrict__ h2, const float* __restrict__ mw1, const float* __restrict__ mb1,
    float* __restrict__ PQ)
{
  __shared__ float wl[64][HID];   // 32KB
  __shared__ float al[128][68];   // 34.8KB
  const int t = threadIdx.x;
  const int m0 = blockIdx.x * 128;
  const int n0 = blockIdx.y * 128;      // never straddles 512
  const int tc = t % 16, tr = t / 16;
  const int basek = (n0 >= 512) ? HID : 0;
  const int cbase = n0 & 511;

  float acc[8][8];
#pragma unroll
  for (int i = 0; i < 8; i++)
#pragma unroll
    for (int j = 0; j < 8; j++) acc[i][j] = 0.f;

  for (int ch = 0; ch < 2; ++ch) {
    __syncthreads();
    for (int i = t; i < 64 * 32; i += 256) {
      int kk = i / 32, q = i % 32;
      *(float4*)&wl[kk][q * 4] =
          *(const float4*)(mw1 + (size_t)(basek + ch * 64 + kk) * 512 + cbase + q * 4);
    }
    for (int i = t; i < 128 * 16; i += 256) {
      int r = i / 16, q = i % 16;
      int gr = m0 + r; if (gr >= NTOT) gr = NTOT - 1;
      *(float4*)&al[r][q * 4] = *(const float4*)(h2 + (size_t)gr * HID + ch * 64 + q * 4);
    }
    __syncthreads();
    for (int k4 = 0; k4 < 16; ++k4) {
      float4 a4[8];
#pragma unroll
      for (int i = 0; i < 8; i++)
        a4[i] = *(const float4*)&al[tr * 8 + i][k4 * 4];
#pragma unroll
      for (int kk = 0; kk < 4; kk++) {
        float wv0[4], wv1[4];
        *(float4*)wv0 = *(const float4*)&wl[k4 * 4 + kk][tc * 4];
        *(float4*)wv1 = *(const float4*)&wl[k4 * 4 + kk][64 + tc * 4];
#pragma unroll
        for (int i = 0; i < 8; i++) {
          const float av = (&a4[i].x)[kk];
#pragma unroll
          for (int j = 0; j < 4; j++) {
            acc[i][j]     += av * wv0[j];
            acc[i][4 + j] += av * wv1[j];
          }
        }
      }
    }
  }
#pragma unroll
  for (int i = 0; i < 8; i++) {
    const int r = m0 + tr * 8 + i;
    if (r < NTOT) {
      float4 o0, o1;
#pragma unroll
      for (int j = 0; j < 4; j++) {
        float c0 = acc[i][j]     + (basek == 0 ? mb1[cbase + tc * 4 + j]      : 0.f);
        float c1 = acc[i][4 + j] + (basek == 0 ? mb1[cbase + 64 + tc * 4 + j] : 0.f);
        (&o0.x)[j] = c0; (&o1.x)[j] = c1;
      }
      float* op = PQ + (size_t)r * 1024 + n0;
      *(float4*)(op + tc * 4)      = o0;
      *(float4*)(op + 64 + tc * 4) = o1;
    }
  }
}

// ---------------------------------------------------------------------------
// edge_sort v2: per-graph. Stage P/Q 64-col chunks into stride-66 LDS
// (float2 reads: pair-phase (33*sl+j)%16 covers all 16 phases), score 800
// edges (fp64 chunk accumulation), then bitonic sort + top-K split +
// presence + local relabel ranks — all in one block. ~65KB LDS, 2 blocks/CU.
// ---------------------------------------------------------------------------
__global__ __launch_bounds__(256) void edge_sort_kernel(
    const float* __restrict__ PQ, const int* __restrict__ ei,
    const float* __restrict__ mw2, const float* __restrict__ mb2,
    float* __restrict__ out_es,
    int* __restrict__ keptEid, int* __restrict__ dropEid,
    int* __restrict__ cLocal, int* __restrict__ fLocal,
    int* __restrict__ cCount, int* __restrict__ fCount)
{
  __shared__ __align__(16) float Pl[NPG][66];
  __shared__ __align__(16) float Ql[NPG][66];
  __shared__ __align__(16) float w2l[512];
  __shared__ unsigned char esrcL[EPG];
  __shared__ unsigned char edstL[EPG];
  __shared__ unsigned long long keys[1024];
  __shared__ int cpres[NPG];
  __shared__ int fpres[NPG];

  const int g = blockIdx.x, t = threadIdx.x;
  const int nb = g * NPG;

  for (int e = t; e < EPG; e += 256) {
    int ge = g * EPG + e;
    esrcL[e] = (unsigned char)(ei[ge] - nb);
    edstL[e] = (unsigned char)(ei[ETOT + ge] - nb);
  }
  for (int i = t; i < 128; i += 256) *(float4*)&w2l[i * 4] = *(const float4*)(mw2 + i * 4);
  for (int i = t; i < NPG; i += 256) { cpres[i] = 0; fpres[i] = 0; }
  __syncthreads();

  int sl[4], dl[4];
#pragma unroll
  for (int m = 0; m < 4; m++) {
    const int e = t + 256 * m;
    const int ec = e < EPG ? e : 0;
    sl[m] = esrcL[ec]; dl[m] = edstL[ec];
  }
  double accd[4];
#pragma unroll
  for (int m = 0; m < 4; m++) accd[m] = 0.;

  for (int ch = 0; ch < 8; ++ch) {
    __syncthreads();   // previous edge phase done reading Pl/Ql
    for (int i = t; i < NPG * 32; i += 256) {
      const int r = i >> 5, q = i & 31;
      const float* src = PQ + (size_t)(nb + r) * 1024 + ch * 64 + q * 2;
      *(float2*)&Pl[r][q * 2] = *(const float2*)src;
      *(float2*)&Ql[r][q * 2] = *(const float2*)(src + 512);
    }
    __syncthreads();
#pragma unroll
    for (int m = 0; m < 4; m++) {
      double aa = 0.;
      for (int j4 = 0; j4 < 16; ++j4) {
        const float2 pa = *(const float2*)&Pl[sl[m]][j4 * 4];
        const float2 pb = *(const float2*)&Pl[sl[m]][j4 * 4 + 2];
        const float2 qa = *(const float2*)&Ql[dl[m]][j4 * 4];
        const float2 qb = *(const float2*)&Ql[dl[m]][j4 * 4 + 2];
        const float4 w = *(const float4*)&w2l[ch * 64 + j4 * 4];
        const float s = fmaxf(pa.x + qa.x, 0.f) * w.x + fmaxf(pa.y + qa.y, 0.f) * w.y
                      + fmaxf(pb.x + qb.x, 0.f) * w.z + fmaxf(pb.y + qb.y, 0.f) * w.w;
        aa += (double)s;
      }
      accd[m] += aa;
    }
  }

  // scores out + sort keys
  const double b2v = (double)mb2[0];
#pragma unroll
  for (int m = 0; m < 4; m++) {
    const int e = t + 256 * m;
    if (e < EPG) {
      const float sc = (float)(accd[m] + b2v);
      out_es[g * EPG + e] = sc;
      const unsigned int bb = __float_as_uint(sc);
      const unsigned int mm = (bb & 0x80000000u) ? (~bb) : (bb | 0x80000000u);
      keys[e] = ((unsigned long long)(~mm) << 32) | (unsigned int)e;
    }
  }
  if (t >= 32) keys[t + 768] = 0xFFFFFFFFFFFFFFFFull;   // pads 800..1023
  __syncthreads();

  for (int k = 2; k <= 1024; k <<= 1) {
    for (int j = k >> 1; j > 0; j >>= 1) {
      for (int i = t; i < 1024; i += 256) {
        const int l = i ^ j;
        if (l > i) {
          const bool up = ((i & k) == 0);
          const unsigned long long va = keys[i], vb = keys[l];
          if ((va > vb) == up) { keys[i] = vb; keys[l] = va; }
        }
      }
      __syncthreads();
    }
  }

  for (int r = t; r < EPG; r += 256) {
    const int el = (int)(unsigned int)keys[r];
    const int ge = g * EPG + el;
    const int s0 = esrcL[el], d0 = edstL[el];
    if (r < KKEEP) {
      keptEid[g * KKEEP + r] = ge;
      cpres[s0] = 1; cpres[d0] = 1;
    } else {
      dropEid[g * KDROP + (r - KKEEP)] = ge;
      fpres[s0] = 1; fpres[d0] = 1;
    }
  }
  __syncthreads();

  if (t == 0) {
    int cc = 0;
    for (int v = 0; v < NPG; v++) { const int pr = cpres[v]; cLocal[nb + v] = pr ? cc : -1; cc += pr; }
    cCount[g] = cc;
  }
  if (t == 64) {
    int fc = 0;
    for (int v = 0; v < NPG; v++) { const int pr = fpres[v]; fLocal[nb + v] = pr ? fc : -1; fc += pr; }
    fCount[g] = fc;
  }
}

__global__ __launch_bounds__(512) void offsets_kernel(
    const int* __restrict__ cCount, const int* __restrict__ fCount,
    int* __restrict__ cOff, int* __restrict__ fOff)
{
  __shared__ int sc[512];
  __shared__ int sf[512];
  const int t = threadIdx.x;
  const int c0 = (t < NG) ? cCount[t] : 0;
  const int f0 = (t < NG) ? fCount[t] : 0;
  sc[t] = c0; sf[t] = f0;
  __syncthreads();
  for (int off = 1; off < 512; off <<= 1) {
    const int ac = (t >= off) ? sc[t - off] : 0;
    const int af = (t >= off) ? sf[t - off] : 0;
    __syncthreads();
    sc[t] += ac; sf[t] += af;
    __syncthreads();
  }
  if (t < NG) { cOff[t] = sc[t] - c0; fOff[t] = sf[t] - f0; }
  if (t == NG - 1) { cOff[NG] = sc[t]; fOff[NG] = sf[t]; }
}

__global__ __launch_bounds__(256) void scatter_kernel(
    const float* __restrict__ h2, const int* __restrict__ cLocal, const int* __restrict__ fLocal,
    const int* __restrict__ cOff, const int* __restrict__ fOff,
    int* __restrict__ nodeIdxC, int* __restrict__ nodeIdxF, float* __restrict__ out)
{
  const int tid = blockIdx.x * 256 + threadIdx.x;
  if (tid >= 2 * NTOT * 32) return;
  const int side = tid >= NTOT * 32 ? 1 : 0;
  const int rem = tid - side * NTOT * 32;
  const int v = rem >> 5, q = rem & 31;
  const int loc = side ? fLocal[v] : cLocal[v];
  if (loc < 0) return;
  const int g = v / NPG;
  const int pos = (side ? fOff[g] : cOff[g]) + loc;
  const float4* srcv = (const float4*)(h2 + (size_t)v * HID);
  float4* dstv = (float4*)(out + (side ? OFF_FX : OFF_CX) + (size_t)pos * HID);
  dstv[q] = srcv[q];
  if (q == 0) {
    (side ? nodeIdxF : nodeIdxC)[v] = pos;
    out[(side ? OFF_FB : OFF_CB) + pos] = (float)g;
  }
}

__global__ __launch_bounds__(256) void fill_kernel(
    const int* __restrict__ cOff, const int* __restrict__ fOff, float* __restrict__ out)
{
  const int tid = blockIdx.x * 256 + threadIdx.x;
  if (tid >= 2 * NTOT * 32) return;
  const int side = tid >= NTOT * 32 ? 1 : 0;
  const int rem = tid - side * NTOT * 32;
  const int r = rem >> 5, q = rem & 31;
  const int total = side ? fOff[NG] : cOff[NG];
  if (r < total) return;
  float4 z; z.x = 0.f; z.y = 0.f; z.z = 0.f; z.w = 0.f;
  ((float4*)(out + (side ? OFF_FX : OFF_CX)))[(size_t)r * 32 + q] = z;
  if (q == 0) out[(side ? OFF_FB : OFF_CB) + r] = -1.0f;
}

__global__ __launch_bounds__(256) void edgeout_kernel(
    const int* __restrict__ ei, const float* __restrict__ ea, const float* __restrict__ scores,
    const int* __restrict__ keptEid, const int* __restrict__ dropEid,
    const int* __restrict__ nodeIdxC, const int* __restrict__ nodeIdxF, float* __restrict__ out)
{
  const int tid = blockIdx.x * 256 + threadIdx.x;
  if (tid >= ETOT) return;
  if (tid < NG * KKEEP) {
    const int ge = keptEid[tid];
    out[OFF_CEI + tid] = (float)nodeIdxC[ei[ge]];
    out[OFF_CEI + 320000 + tid] = (float)nodeIdxC[ei[ETOT + ge]];
    out[OFF_CATTR + tid] = ea[ge];
    out[OFF_CW + tid] = scores[ge];
  } else {
    const int i = tid - NG * KKEEP;
    const int ge = dropEid[i];
    out[OFF_FEI + i] = (float)nodeIdxF[ei[ge]];
    out[OFF_FEI + 80000 + i] = (float)nodeIdxF[ei[ETOT + ge]];
    out[OFF_FATTR + i] = ea[ge];
    out[OFF_FW + i] = -scores[ge];
  }
}

extern "C" void kernel_launch(void* const* d_in, const int* in_sizes, int n_in,
                              void* d_out, int out_size, void* d_ws, size_t ws_size,
                              hipStream_t stream) {
  const float* x    = (const float*)d_in[0];
  const int*   ei   = (const int*)d_in[1];
  const float* ea   = (const float*)d_in[2];
  const float* c1w1 = (const float*)d_in[4];
  const float* c1b1 = (const float*)d_in[5];
  const float* c1w2 = (const float*)d_in[6];
  const float* c1w3 = (const float*)d_in[7];
  const float* c1b3 = (const float*)d_in[8];
  const float* c2w1 = (const float*)d_in[9];
  const float* c2b1 = (const float*)d_in[10];
  const float* c2w2 = (const float*)d_in[11];
  const float* c2w3 = (const float*)d_in[12];
  const float* c2b3 = (const float*)d_in[13];
  const float* mw1  = (const float*)d_in[14];
  const float* mb1  = (const float*)d_in[15];
  const float* mw2  = (const float*)d_in[16];
  const float* mb2  = (const float*)d_in[17];
  float* out = (float*)d_out;

  char* p = (char*)d_ws;
  auto carve = [&](size_t bytes) { void* r = (void*)p; p += (bytes + 255) & ~(size_t)255; return r; };
  // persistent-through-pipeline allocations first
  float* h2      = (float*)carve((size_t)NTOT * HID * 4);
  int* keptEid   = (int*)carve((size_t)NG * KKEEP * 4);
  int* dropEid   = (int*)carve((size_t)NG * KDROP * 4);
  int* cLocal    = (int*)carve((size_t)NTOT * 4);
  int* fLocal    = (int*)carve((size_t)NTOT * 4);
  int* cCount    = (int*)carve((size_t)NG * 4);
  int* fCount    = (int*)carve((size_t)NG * 4);
  int* cOff      = (int*)carve((size_t)(NG + 1) * 4);
  int* fOff      = (int*)carve((size_t)(NG + 1) * 4);
  int* nodeIdxC  = (int*)carve((size_t)NTOT * 4);
  int* nodeIdxF  = (int*)carve((size_t)NTOT * 4);
  // union region: {h1, ybuf, elist2, ecnt, sdeg} (conv phase) OVERLAID BY
  // PQ [NTOT][1024] (score phase) — conv temporaries are dead once conv2
  // has written h2.
  char* ub = (char*)carve((size_t)NTOT * 1024 * 4);
  float* PQ      = (float*)ub;
  float* h1      = (float*)ub;
  float* ybuf    = (float*)(ub + (size_t)NTOT * HID * 4);
  float2* elist2 = (float2*)(ub + (size_t)2 * NTOT * HID * 4);
  int* ecnt      = (int*)(ub + (size_t)2 * NTOT * HID * 4 + (size_t)NTOT * MAXDEG * 8);
  float* sdeg    = (float*)(ub + (size_t)2 * NTOT * HID * 4 + (size_t)NTOT * MAXDEG * 8 + (size_t)NTOT * 4);

  const int MT = (NTOT + 127) / 128;

  prep_kernel<<<NG, 128, 0, stream>>>(ei, ea, elist2, ecnt, sdeg);
  preagg_kernel<INDIM><<<NG, 512, 0, stream>>>(x, elist2, ecnt, ybuf);
  conv_gemm_kernel<INDIM, true><<<MT, 256, 0, stream>>>(ybuf, x, sdeg, c1w1, c1w2, c1w3, c1b1, c1b3, h1);
  preagg_kernel<HID><<<NG, 512, 0, stream>>>(h1, elist2, ecnt, ybuf);
  conv_gemm_kernel<HID, false><<<MT, 256, 0, stream>>>(ybuf, h1, sdeg, c2w1, c2w2, c2w3, c2b1, c2b3, h2);
  dim3 pqgrid(MT, 8);
  pq_gemm_kernel<<<pqgrid, 256, 0, stream>>>(h2, mw1, mb1, PQ);
  edge_sort_kernel<<<NG, 256, 0, stream>>>(PQ, ei, mw2, mb2, out + OFF_ES,
                                           keptEid, dropEid, cLocal, fLocal, cCount, fCount);
  offsets_kernel<<<1, 512, 0, stream>>>(cCount, fCount, cOff, fOff);
  const int sc_threads = 2 * NTOT * 32;
  scatter_kernel<<<(sc_threads + 255) / 256, 256, 0, stream>>>(h2, cLocal, fLocal, cOff, fOff, nodeIdxC, nodeIdxF, out);
  fill_kernel<<<(sc_threads + 255) / 256, 256, 0, stream>>>(cOff, fOff, out);
  edgeout_kernel<<<(ETOT + 255) / 256, 256, 0, stream>>>(ei, ea, out + OFF_ES, keptEid, dropEid, nodeIdxC, nodeIdxF, out);
}